// Round 7
// baseline (244.166 us; speedup 1.0000x reference)
//
#include <hip/hip_runtime.h>

// DWT db4 depthwise stride-2 decomposition.
// x: [B=32, T=16384, C=64] f32 -> out: [B, T2=8190, 2C=128] f32
// out[b,t,c]    = sum_k lo[k] * x[b, reflect(2t+k-1), c]      (c < 64)
// out[b,t,64+c] = sum_k hi[k] * x[b, reflect(2t+k-1), c]
//
// R7: persistent blocks + double-buffered LDS pipeline (T3-minimum 2-phase).
// R6 post-mortem: doubling resident blocks/CU (4->8, 100% occupancy) gave
// -2us -- TLP is NOT the missing ingredient.  Every prior version's block
// has a gappy load stream (issue -> full drain -> compute -> retire: ~40%
// load duty).  Fix: each block stages tile i+1 BEFORE computing tile i, so
// the global_load_lds DMA flies under the compute and the barrier-drain is
// already satisfied.  Recipe (guide T3): STAGE(next buf); compute(cur buf);
// __syncthreads() [= vmcnt(0)+lgkmcnt(0)+barrier]; swap.  sched_barrier(0)
// pins the stage VMEM issue above the compute (the DMA has no register
// result, so the scheduler would otherwise happily sink it).
// 1024 persistent blocks (4/CU, 2x18.4KB LDS), 8 consecutive tiles each
// (re-staged 8-row tile overlap hits L2 on the same XCD).

#define BT      32
#define TT      16384
#define CC      64
#define T2      8190        // T/2 - 2
#define OC      128         // 2*CC
#define TBLK    32          // outputs per tile
#define NROWS   72          // staged rows: 70 needed + 2 pad for 1KB chunking
#define NCHUNK  18          // NROWS*256B / 1024B
#define NTILE_T 256         // t-tiles per batch (8192/32)
#define TPB     8           // tiles per persistent block
#define NBLK    1024        // (NTILE_T*BT)/TPB

__global__ __launch_bounds__(256, 4) void dwt_db4_pipe_kernel(
    const float* __restrict__ x,
    const float* __restrict__ dec_lo,
    const float* __restrict__ dec_hi,
    float* __restrict__ out)
{
    __shared__ float lds[2][NROWS * CC];       // 2 x 18432 B = 36864 B

    const int tid  = threadIdx.x;
    const int wave = tid >> 6;
    const int lane = tid & 63;
    const int cg   = tid & 15;                 // channel group (4 ch, float4)
    const int sl   = tid >> 4;                 // pair slot 0..15
    const int c4   = cg * 4;
    const int g0   = blockIdx.x * TPB;         // first tile of this block

    // Filters: uniform addresses -> scalar broadcast loads.
    float flo[8], fhi[8];
    #pragma unroll
    for (int k = 0; k < 8; ++k) { flo[k] = dec_lo[k]; fhi[k] = dec_hi[k]; }

    // ---- stage tile g into LDS buffer dst (zero-register DMA) -----------
    auto stage = [&](int g, float* dst) {
        const int b        = g >> 8;           // g / NTILE_T
        const int t0       = (g & 255) * TBLK;
        const int row_base = (t0 == 0) ? 0 : (2 * t0 - 1);
        const float* xb    = x + (size_t)b * TT * CC;
        const float* gsrc  = xb + (size_t)row_base * CC + lane * 4;
        const float* gend  = xb + (size_t)TT * CC - 4;   // last valid float4
        #pragma unroll
        for (int j = 0; j < 5; ++j) {
            const int c = wave + j * 4;        // 18 chunks over 4 waves
            if (c < NCHUNK) {
                const float* gp = gsrc + c * 256;        // 1KB per chunk
                gp = (gp > gend) ? gend : gp;            // tail clamp (padding
                                                         // rows never read:
                                                         // reflect stays <= T-1)
                __builtin_amdgcn_global_load_lds(
                    (const __attribute__((address_space(1))) unsigned int*)gp,
                    (__attribute__((address_space(3))) unsigned int*)&dst[c * 256],
                    16, 0, 0);
            }
        }
    };

    // ---- compute tile g from LDS buffer buf (R6 pair shape) -------------
    auto compute = [&](int g, const float* buf) {
        const int b        = g >> 8;
        const int t0       = (g & 255) * TBLK;
        const int row_base = (t0 == 0) ? 0 : (2 * t0 - 1);
        const int t        = t0 + sl * 2;

        float4 w[10];
        #pragma unroll
        for (int i = 0; i < 10; ++i) {
            int m  = 2 * t - 1 + i;                           // global row
            int mm = m < 0 ? -m : m;                          // left reflect
            mm     = mm > (TT - 1) ? 2 * (TT - 1) - mm : mm;  // right reflect
            w[i] = *reinterpret_cast<const float4*>(&buf[(mm - row_base) * CC + c4]);
        }

        float4 alo0, ahi0, alo1, ahi1;
        alo0.x = alo0.y = alo0.z = alo0.w = 0.0f;
        ahi0.x = ahi0.y = ahi0.z = ahi0.w = 0.0f;
        alo1.x = alo1.y = alo1.z = alo1.w = 0.0f;
        ahi1.x = ahi1.y = ahi1.z = ahi1.w = 0.0f;

        #pragma unroll
        for (int k = 0; k < 8; ++k) {
            const float4 v0 = w[k];
            const float4 v1 = w[k + 2];
            alo0.x = fmaf(flo[k], v0.x, alo0.x);
            alo0.y = fmaf(flo[k], v0.y, alo0.y);
            alo0.z = fmaf(flo[k], v0.z, alo0.z);
            alo0.w = fmaf(flo[k], v0.w, alo0.w);
            ahi0.x = fmaf(fhi[k], v0.x, ahi0.x);
            ahi0.y = fmaf(fhi[k], v0.y, ahi0.y);
            ahi0.z = fmaf(fhi[k], v0.z, ahi0.z);
            ahi0.w = fmaf(fhi[k], v0.w, ahi0.w);

            alo1.x = fmaf(flo[k], v1.x, alo1.x);
            alo1.y = fmaf(flo[k], v1.y, alo1.y);
            alo1.z = fmaf(flo[k], v1.z, alo1.z);
            alo1.w = fmaf(flo[k], v1.w, alo1.w);
            ahi1.x = fmaf(fhi[k], v1.x, ahi1.x);
            ahi1.y = fmaf(fhi[k], v1.y, ahi1.y);
            ahi1.z = fmaf(fhi[k], v1.z, ahi1.z);
            ahi1.w = fmaf(fhi[k], v1.w, ahi1.w);
        }

        float* ob = out + (size_t)b * T2 * OC + (size_t)t * OC + c4;
        if (t < T2) {
            *reinterpret_cast<float4*>(ob)      = alo0;
            *reinterpret_cast<float4*>(ob + CC) = ahi0;
        }
        if (t + 1 < T2) {
            *reinterpret_cast<float4*>(ob + OC)      = alo1;
            *reinterpret_cast<float4*>(ob + OC + CC) = ahi1;
        }
    };

    // ---- 2-phase pipeline over TPB tiles --------------------------------
    stage(g0, lds[0]);
    __syncthreads();                            // drain prologue stage

    #pragma unroll 2                            // makes (i & 1) compile-time
    for (int i = 0; i < TPB; ++i) {
        const int cur = i & 1;
        if (i + 1 < TPB)
            stage(g0 + i + 1, lds[cur ^ 1]);    // DMA flies under compute
        __builtin_amdgcn_sched_barrier(0);      // pin stage issue above FMAs
        compute(g0 + i, lds[cur]);
        __syncthreads();                        // vmcnt(0)+lgkmcnt(0)+barrier:
                                                // next buf ready, cur buf free
    }
}

extern "C" void kernel_launch(void* const* d_in, const int* in_sizes, int n_in,
                              void* d_out, int out_size, void* d_ws, size_t ws_size,
                              hipStream_t stream)
{
    const float* x      = (const float*)d_in[0];
    const float* dec_lo = (const float*)d_in[1];
    const float* dec_hi = (const float*)d_in[2];
    float*       out    = (float*)d_out;

    dim3 block(256);
    dim3 grid(NBLK);      // 1024 persistent blocks x 8 tiles = 8192 tiles

    hipLaunchKernelGGL(dwt_db4_pipe_kernel, grid, block, 0, stream,
                       x, dec_lo, dec_hi, out);
}

// Round 9
// 231.805 us; speedup vs baseline: 1.0533x; 1.0533x over previous
//
#include <hip/hip_runtime.h>
#include <stdint.h>

// DWT db4 depthwise stride-2 decomposition.
// x: [B=32, T=16384, C=64] f32 -> out: [B, T2=8190, 2C=128] f32
// out[b,t,c]    = sum_k lo[k] * x[b, reflect(2t+k-1), c]      (c < 64)
// out[b,t,64+c] = sum_k hi[k] * x[b, reflect(2t+k-1), c]
//
// R8 resubmit (R8 bench was a container-acquisition infra failure -- same
// error as R1/R2, where the identical source later ran fine; audit found no
// way for this kernel to hang or fault a container).
//
// Barrier-free counted-vmcnt register pipeline (T4 adapted to streaming).
// R3-R7 post-mortem: every structure so far drains vmcnt to 0 once per work
// unit (compiler-inserted before use / at __syncthreads).  Compute (~0.6us)
// << load round-trip (~2us), so each wave's read stream is gappy regardless
// of TLP (R6: 100% occupancy, -2us) or DMA bursts (R5) or LDS dbuf (R7:
// barrier's vmcnt(0) waits for the NEXT tile's stage -> worse, 84us).
// Fix: inline-asm global_load_dwordx4 with asm-PINNED outputs (compiler
// cannot serialize via register reuse, which killed R3/R4) + counted
// s_waitcnt vmcnt(10) that never reaches 0 in steady state.  Each wave holds
// ~10 KB of reads in flight continuously; 16 waves/CU -> ~160 KB/CU, the
// regime where the 6.5 TB/s fill kernels operate.
// Accounting (all memory asm has "memory" clobber -> program-order issue):
//   at each wait: outstanding = [prev loads 10][prev stores 4][new 10]
//   vmcnt(10) drains prev loads + stores, leaves the new 10 in flight.
//   rule #18: sched_barrier(0) after each wait stops fmaf hoisting
//   ("memory" clobber doesn't order pure-VALU ops).
// Grid: 1024 blocks x 256 thr = 262144 threads, exactly resident at 4
// waves/SIMD (VGPR<=128), zero tail; 8 items/thread; item = (batch, pair of
// outputs, 4-channel group).

typedef float f32x4 __attribute__((ext_vector_type(4)));

#define BT       32
#define TT       16384
#define CC       64
#define T2       8190
#define OC       128
#define PAIR_SL  4096         // padded pair slots per batch (4095 real)
#define NT       262144       // total threads = 1024 * 256
#define KIT      8            // items per thread: 32*4096*16 / NT

struct Item {
    const float* src;         // x + b*T*C + cg*4
    float*       dst;         // out + b*T2*OC + t*OC + cg*4
    int          t;
    bool         valid;
};

__device__ __forceinline__ Item decode(int g, const float* __restrict__ x,
                                       float* __restrict__ out)
{
    const int cg   = g & 15;
    const int pair = (g >> 4) & (PAIR_SL - 1);
    const int b    = g >> 16;
    Item it;
    it.t     = pair * 2;
    it.src   = x   + (size_t)b * TT * CC + cg * 4;
    it.dst   = out + (size_t)b * T2 * OC + (size_t)(pair * 2) * OC + cg * 4;
    it.valid = pair < (PAIR_SL - 1);      // pair 4095 -> t=8190,8191 invalid
    return it;
}

// Issue the 10-row window as pinned-register loads.  Data is NOT valid until
// an s_waitcnt; the compiler doesn't know that, so callers must wait+fence
// before touching w.  Reflect keeps every address in [0, T-1] even for the
// padded pair slot.
__device__ __forceinline__ void issue10(const Item& it, f32x4 (&w)[10])
{
    #pragma unroll
    for (int i = 0; i < 10; ++i) {
        int m  = 2 * it.t - 1 + i;
        int mm = m < 0 ? -m : m;                          // left reflect
        mm     = mm > (TT - 1) ? 2 * (TT - 1) - mm : mm;  // right reflect
        const uint64_t a = (uint64_t)(it.src + (size_t)mm * CC);
        asm volatile("global_load_dwordx4 %0, %1, off"
                     : "=v"(w[i]) : "v"(a) : "memory");
    }
}

__device__ __forceinline__ void compute_store(const f32x4 (&w)[10],
                                              const Item& it,
                                              const float* __restrict__ flo,
                                              const float* __restrict__ fhi)
{
    if (!it.valid) return;
    f32x4* ob = (f32x4*)it.dst;           // 16B-aligned (cg*4 floats)
    f32x4 a;

    a = flo[0] * w[0];                    // output t, lo
    #pragma unroll
    for (int k = 1; k < 8; ++k) a += flo[k] * w[k];
    ob[0] = a;

    a = fhi[0] * w[0];                    // output t, hi
    #pragma unroll
    for (int k = 1; k < 8; ++k) a += fhi[k] * w[k];
    ob[16] = a;                           // +64 floats

    a = flo[0] * w[2];                    // output t+1, lo
    #pragma unroll
    for (int k = 1; k < 8; ++k) a += flo[k] * w[k + 2];
    ob[32] = a;                           // +128 floats (next row)

    a = fhi[0] * w[2];                    // output t+1, hi
    #pragma unroll
    for (int k = 1; k < 8; ++k) a += fhi[k] * w[k + 2];
    ob[48] = a;
}

__global__ __launch_bounds__(256, 4) void dwt_db4_stream_kernel(
    const float* __restrict__ x,
    const float* __restrict__ dec_lo,
    const float* __restrict__ dec_hi,
    float* __restrict__ out)
{
    const int tid = blockIdx.x * 256 + threadIdx.x;

    // Filters -> SGPR (readfirstlane makes uniformity explicit), freeing
    // 16 VGPRs; fma with one SGPR source is legal.
    float flo[8], fhi[8];
    #pragma unroll
    for (int k = 0; k < 8; ++k) {
        flo[k] = __int_as_float(
            __builtin_amdgcn_readfirstlane(__float_as_int(dec_lo[k])));
        fhi[k] = __int_as_float(
            __builtin_amdgcn_readfirstlane(__float_as_int(dec_hi[k])));
    }

    f32x4 wA[10], wB[10];                 // 80 asm-pinned VGPRs (the point)

    int gA = tid;
    Item iA = decode(gA, x, out);
    issue10(iA, wA);                      // prologue: slot A in flight

    #pragma unroll
    for (int k = 0; k < KIT / 2; ++k) {
        // --- slot B prefetch, then consume A -------------------------------
        const int gB = gA + NT;
        Item iB = decode(gB, x, out);
        issue10(iB, wB);
        asm volatile("s_waitcnt vmcnt(10)" ::: "memory");  // A done, B in flight
        __builtin_amdgcn_sched_barrier(0);                 // rule #18 fence
        compute_store(wA, iA, flo, fhi);

        // --- slot A prefetch (next round), then consume B ------------------
        if (k < KIT / 2 - 1) {
            gA = gB + NT;
            iA = decode(gA, x, out);
            issue10(iA, wA);
            asm volatile("s_waitcnt vmcnt(10)" ::: "memory"); // B done, A in flight
        } else {
            asm volatile("s_waitcnt vmcnt(0)" ::: "memory");  // epilogue drain
        }
        __builtin_amdgcn_sched_barrier(0);
        compute_store(wB, iB, flo, fhi);
    }
}

extern "C" void kernel_launch(void* const* d_in, const int* in_sizes, int n_in,
                              void* d_out, int out_size, void* d_ws, size_t ws_size,
                              hipStream_t stream)
{
    const float* x      = (const float*)d_in[0];
    const float* dec_lo = (const float*)d_in[1];
    const float* dec_hi = (const float*)d_in[2];
    float*       out    = (float*)d_out;

    dim3 block(256);
    dim3 grid(NT / 256);      // 1024 blocks: exactly resident, zero tail

    hipLaunchKernelGGL(dwt_db4_stream_kernel, grid, block, 0, stream,
                       x, dec_lo, dec_hi, out);
}

// Round 11
// 229.100 us; speedup vs baseline: 1.0658x; 1.0118x over previous
//
#include <hip/hip_runtime.h>

// DWT db4 depthwise stride-2 decomposition.
// x: [B=32, T=16384, C=64] f32 -> out: [B, T2=8190, 2C=128] f32
// out[b,t,c]    = sum_k lo[k] * x[b, reflect(2t+k-1), c]      (c < 64)
// out[b,t,64+c] = sum_k hi[k] * x[b, reflect(2t+k-1), c]
// reflect: m<0 -> -m ; m>T-1 -> 2(T-1)-m
//
// FINAL (R11 = R10 resubmit; R10 bench was a container-acquisition infra
// failure, same transient as R1/R2 and R8 where identical source later ran
// fine).  Byte-identical revert to the session-best R2 structure (227.2us
// measured R0; best of 6 structural variants).
// Mechanisms tried and falsified against this baseline:
//   R3/R4 wider reg window         -> 88-91us (hipcc minimizes VGPR, serializes)
//   R5/R6 global_load_lds burst    -> ~70us   (4 and 8 blocks/CU, 100% occ)
//   R7    LDS dbuf 2-phase         -> 84us    (barrier vmcnt(0) drains next stage)
//   R9    asm counted-vmcnt stream -> ~71us   (pinned regs, vmcnt(10) steady)
// No pipe saturated in any variant (VALU<=8%, HBM<=31%, conflicts 0).
// One thread = (4 channels via float4) x (pair of outputs t,t+1); the pair
// needs input rows 2t-1..2t+8 (10 rows), all loads independent and issued
// before any use.  Logical re-read (2.5x) absorbed by L1/L2/L3.

#define BT   32
#define TT   16384
#define CC   64
#define T2   8190       // T/2 - 2
#define OC   128        // 2*CC
#define NPAIR (T2 / 2)  // 4095

__global__ __launch_bounds__(256) void dwt_db4_pair_kernel(
    const float* __restrict__ x,
    const float* __restrict__ dec_lo,
    const float* __restrict__ dec_hi,
    float* __restrict__ out)
{
    const int tid  = threadIdx.x;
    const int cg   = tid & 15;               // channel group: 4 ch via float4
    const int tp   = tid >> 4;               // 0..15: pair slot within block
    const int pair = blockIdx.x * 16 + tp;
    const int b    = blockIdx.y;
    if (pair >= NPAIR) return;

    const int t  = pair * 2;
    const int c4 = cg * 4;

    // Filters: uniform addresses -> scalar broadcast loads.
    float flo[8], fhi[8];
    #pragma unroll
    for (int k = 0; k < 8; ++k) { flo[k] = dec_lo[k]; fhi[k] = dec_hi[k]; }

    const float* __restrict__ xb = x + (size_t)b * TT * CC;

    // 10-row window, all loads independent.
    const int m0 = 2 * t - 1;
    float4 w[10];
    #pragma unroll
    for (int i = 0; i < 10; ++i) {
        int m  = m0 + i;
        int mm = m < 0 ? -m : m;                          // left reflect (t==0)
        mm     = mm > (TT - 1) ? 2 * (TT - 1) - mm : mm;  // right reflect (tail)
        w[i] = *reinterpret_cast<const float4*>(xb + (size_t)mm * CC + c4);
    }

    float4 alo0, ahi0, alo1, ahi1;
    alo0.x = alo0.y = alo0.z = alo0.w = 0.0f;
    ahi0.x = ahi0.y = ahi0.z = ahi0.w = 0.0f;
    alo1.x = alo1.y = alo1.z = alo1.w = 0.0f;
    ahi1.x = ahi1.y = ahi1.z = ahi1.w = 0.0f;

    #pragma unroll
    for (int k = 0; k < 8; ++k) {
        // output t uses rows w[0..7], output t+1 uses rows w[2..9]
        alo0.x = fmaf(flo[k], w[k].x, alo0.x);
        alo0.y = fmaf(flo[k], w[k].y, alo0.y);
        alo0.z = fmaf(flo[k], w[k].z, alo0.z);
        alo0.w = fmaf(flo[k], w[k].w, alo0.w);
        ahi0.x = fmaf(fhi[k], w[k].x, ahi0.x);
        ahi0.y = fmaf(fhi[k], w[k].y, ahi0.y);
        ahi0.z = fmaf(fhi[k], w[k].z, ahi0.z);
        ahi0.w = fmaf(fhi[k], w[k].w, ahi0.w);

        alo1.x = fmaf(flo[k], w[k + 2].x, alo1.x);
        alo1.y = fmaf(flo[k], w[k + 2].y, alo1.y);
        alo1.z = fmaf(flo[k], w[k + 2].z, alo1.z);
        alo1.w = fmaf(flo[k], w[k + 2].w, alo1.w);
        ahi1.x = fmaf(fhi[k], w[k + 2].x, ahi1.x);
        ahi1.y = fmaf(fhi[k], w[k + 2].y, ahi1.y);
        ahi1.z = fmaf(fhi[k], w[k + 2].z, ahi1.z);
        ahi1.w = fmaf(fhi[k], w[k + 2].w, ahi1.w);
    }

    float* __restrict__ ob = out + (size_t)b * T2 * OC + (size_t)t * OC;
    *reinterpret_cast<float4*>(ob + c4)           = alo0;
    *reinterpret_cast<float4*>(ob + CC + c4)      = ahi0;
    *reinterpret_cast<float4*>(ob + OC + c4)      = alo1;
    *reinterpret_cast<float4*>(ob + OC + CC + c4) = ahi1;
}

extern "C" void kernel_launch(void* const* d_in, const int* in_sizes, int n_in,
                              void* d_out, int out_size, void* d_ws, size_t ws_size,
                              hipStream_t stream)
{
    const float* x      = (const float*)d_in[0];
    const float* dec_lo = (const float*)d_in[1];
    const float* dec_hi = (const float*)d_in[2];
    float*       out    = (float*)d_out;

    dim3 block(256);
    // 16 pairs per block -> ceil(4095/16) = 256 tiles; x 32 batches
    dim3 grid((NPAIR + 15) / 16, BT);

    hipLaunchKernelGGL(dwt_db4_pair_kernel, grid, block, 0, stream,
                       x, dec_lo, dec_hi, out);
}